// Round 9
// baseline (344.702 us; speedup 1.0000x reference)
//
#include <hip/hip_runtime.h>
#include <math.h>

#define N_NODES 10000
#define N_EDGES 160000
#define N_FEAT  512
#define HEADS   8
#define HID     128

typedef __attribute__((ext_vector_type(8))) short bf16x8;
typedef __attribute__((ext_vector_type(4))) float f32x4;

// ---------------------------------------------------------------------------
// fp32 <-> bf16 helpers
// ---------------------------------------------------------------------------
__device__ inline unsigned short f2bf_rne(float f) {
  unsigned int u = __float_as_uint(f);
  unsigned int r = u + 0x7fffu + ((u >> 16) & 1u);
  return (unsigned short)(r >> 16);
}
__device__ inline float bf2f(unsigned int b) {
  return __uint_as_float(b << 16);
}

// ---------------------------------------------------------------------------
// Split fp32 [R][K] into hi/lo bf16 in MFMA-fragment-major layout:
// unit (rb,kq,r) at index (rb*K8+kq)*16+r holds 8 bf16 = A[rb*16+r][kq*8..+8].
// ---------------------------------------------------------------------------
__global__ __launch_bounds__(256)
void split_frag(const float* __restrict__ in, unsigned short* __restrict__ hi,
                unsigned short* __restrict__ lo, int R, int K8, int total) {
  int idx = blockIdx.x * 256 + threadIdx.x;
  if (idx >= total) return;
  int r = idx & 15;
  int t = idx >> 4;
  int kq = t % K8;
  int rb = t / K8;
  int row = rb * 16 + r;
  float v[8] = {0.f, 0.f, 0.f, 0.f, 0.f, 0.f, 0.f, 0.f};
  if (row < R) {
    const float* p = in + (size_t)row * (K8 * 8) + kq * 8;
    float4 a = *(const float4*)p;
    float4 b = *(const float4*)(p + 4);
    v[0] = a.x; v[1] = a.y; v[2] = a.z; v[3] = a.w;
    v[4] = b.x; v[5] = b.y; v[6] = b.z; v[7] = b.w;
  }
  union { unsigned short u[8]; int4 v4; } H, L;
  #pragma unroll
  for (int e = 0; e < 8; ++e) {
    unsigned short hb_ = f2bf_rne(v[e]);
    H.u[e] = hb_;
    L.u[e] = f2bf_rne(v[e] - bf2f(hb_));
  }
  *(int4*)&hi[(size_t)idx * 8] = H.v4;
  *(int4*)&lo[(size_t)idx * 8] = L.v4;
}

// ---------------------------------------------------------------------------
// LDS-free split-bf16 MFMA GEMM with REGISTER DOUBLE-BUFFERED K-loop:
// issue set(k+1)'s 16 b128 loads, MFMA set(k) -> s_waitcnt vmcnt(16), loads
// stay in flight across the MFMA block (hipBLASLt pattern; no barriers).
// Block = 64 rows x 128 cols (full head), 2 waves sharing A-frags (L1 reuse).
// Grid 160*8 swizzled: blk%8 == mtile%8 (XCD L2 A-affinity).
// ---------------------------------------------------------------------------
#define LOAD_SET(AH, AL, BH, BL, AI, BI)                                      \
  _Pragma("unroll")                                                           \
  for (int i = 0; i < 4; ++i) {                                               \
    AH[i] = pAh[(AI) + i * rstep]; AL[i] = pAl[(AI) + i * rstep];             \
    BH[i] = pBh[(BI) + i * rstep]; BL[i] = pBl[(BI) + i * rstep];             \
  }

#define MFMA_TRIPLE(AH, AL, BH, BL)                                           \
  _Pragma("unroll")                                                           \
  for (int i = 0; i < 4; ++i) {                                               \
    _Pragma("unroll")                                                         \
    for (int j = 0; j < 4; ++j) {                                             \
      acc[i][j] = __builtin_amdgcn_mfma_f32_16x16x32_bf16(AH[i], BH[j], acc[i][j], 0, 0, 0); \
      acc[i][j] = __builtin_amdgcn_mfma_f32_16x16x32_bf16(AH[i], BL[j], acc[i][j], 0, 0, 0); \
      acc[i][j] = __builtin_amdgcn_mfma_f32_16x16x32_bf16(AL[i], BH[j], acc[i][j], 0, 0, 0); \
    }                                                                         \
  }

__global__ __launch_bounds__(128, 2)
void gemm_frag(const unsigned short* __restrict__ Afh,
               const unsigned short* __restrict__ Afl,
               const unsigned short* __restrict__ Bfh,
               const unsigned short* __restrict__ Bfl,
               const float* __restrict__ avec,
               unsigned short* __restrict__ hb,
               float* __restrict__ si, float* __restrict__ sj,
               int M, int K) {
  __shared__ float rsi[64][2];
  __shared__ float rsj[64][2];
  int tid = threadIdx.x;
  int wave = tid >> 6, lane = tid & 63;
  int r = lane & 15, q = lane >> 4;

  int blk = blockIdx.x;
  int rr = blk & 7, gg = blk >> 3;
  int head = gg & 7;
  int mtile = (gg >> 3) * 8 + rr;     // blk%8 == mtile%8 -> XCD affinity
  int m0 = mtile * 64;
  int wn = wave * 64;
  int K8 = K >> 3;

  const bf16x8* pAh = (const bf16x8*)Afh;
  const bf16x8* pAl = (const bf16x8*)Afl;
  const bf16x8* pBh = (const bf16x8*)Bfh;
  const bf16x8* pBl = (const bf16x8*)Bfl;
  size_t rstep = (size_t)K8 * 16;
  size_t aidx = (size_t)(m0 >> 4) * rstep + (size_t)q * 16 + r;
  size_t bidx = (size_t)(head * 8 + (wn >> 4)) * rstep + (size_t)q * 16 + r;

  f32x4 acc[4][4] = {};
  bf16x8 ah0[4], al0[4], bh0[4], bl0[4];
  bf16x8 ah1[4], al1[4], bh1[4], bl1[4];

  LOAD_SET(ah0, al0, bh0, bl0, aidx, bidx);
  for (int k0 = 0; k0 < K; k0 += 64) {
    LOAD_SET(ah1, al1, bh1, bl1, aidx + 64, bidx + 64);
    MFMA_TRIPLE(ah0, al0, bh0, bl0);
    aidx += 128; bidx += 128;
    if (k0 + 64 < K) {
      LOAD_SET(ah0, al0, bh0, bl0, aidx, bidx);
    }
    MFMA_TRIPLE(ah1, al1, bh1, bl1);
  }

  // --- epilogue: C/D layout col = r, row = q*4 + reg (per 16x16 frag) ---
  const float* av = avec + (size_t)head * (2 * HID);
  float aiv[4], ajv[4];
  #pragma unroll
  for (int j = 0; j < 4; ++j) {
    int c = wn + j * 16 + r;
    aiv[j] = av[c];
    ajv[j] = av[HID + c];
  }
  #pragma unroll
  for (int i = 0; i < 4; ++i) {
    #pragma unroll
    for (int reg = 0; reg < 4; ++reg) {
      int lrow = i * 16 + q * 4 + reg;
      int row = m0 + lrow;
      float vsi = 0.f, vsj = 0.f;
      #pragma unroll
      for (int j = 0; j < 4; ++j) {
        float v = acc[i][j][reg];
        vsi = fmaf(v, aiv[j], vsi);
        vsj = fmaf(v, ajv[j], vsj);
        if (row < M)
          hb[((size_t)head * M + row) * HID + wn + j * 16 + r] = f2bf_rne(v);
      }
      #pragma unroll
      for (int o = 8; o >= 1; o >>= 1) {
        vsi += __shfl_xor(vsi, o);
        vsj += __shfl_xor(vsj, o);
      }
      if (r == 0) {
        rsi[lrow][wave] = vsi;
        rsj[lrow][wave] = vsj;
      }
    }
  }
  __syncthreads();
  if (tid < 64) {
    int row = m0 + tid;
    if (row < M) {
      si[(size_t)row * HEADS + head] = rsi[tid][0] + rsi[tid][1];
      sj[(size_t)row * HEADS + head] = rsj[tid][0] + rsj[tid][1];
    }
  }
}

// ---------------------------------------------------------------------------
// CSR build
// ---------------------------------------------------------------------------
__global__ void count_kernel(const int* __restrict__ dst, int* __restrict__ deg, int E) {
  int e = blockIdx.x * blockDim.x + threadIdx.x;
  if (e < E) atomicAdd(&deg[dst[e]], 1);
}

__global__ __launch_bounds__(1024)
void scan_kernel(const int* __restrict__ deg, int* __restrict__ off, int N) {
  __shared__ int sums[1024];
  const int PER = 10;
  int tid = threadIdx.x;
  int base = tid * PER;
  int loc[PER];
  int run = 0;
  #pragma unroll
  for (int j = 0; j < PER; ++j) {
    int v = (base + j < N) ? deg[base + j] : 0;
    run += v;
    loc[j] = run;
  }
  sums[tid] = run;
  __syncthreads();
  for (int o = 1; o < 1024; o <<= 1) {
    int v = (tid >= o) ? sums[tid - o] : 0;
    __syncthreads();
    sums[tid] += v;
    __syncthreads();
  }
  int ex = sums[tid] - run;
  if (tid == 0) off[0] = 0;
  #pragma unroll
  for (int j = 0; j < PER; ++j)
    if (base + j < N) off[base + j + 1] = ex + loc[j];
}

__global__ void fill_kernel(const int* __restrict__ src, const int* __restrict__ dst,
                            const int* __restrict__ off, int* __restrict__ cursor,
                            int* __restrict__ ssrc, int E) {
  int e = blockIdx.x * blockDim.x + threadIdx.x;
  if (e < E) {
    int d = dst[e];
    int p = atomicAdd(&cursor[d], 1);
    ssrc[off[d] + p] = src[e];
  }
}

// ---------------------------------------------------------------------------
// Aggregation v4 with FUSED softmax: one wave per (dst, head);
// head = blockIdx.x & 7 (XCD/L2 affinity on head-major hb).
// Pass 1: segment max with one edge per lane + full-wave shfl reduce.
// Pass 2 (gather): 4 grps x 16 lanes, w = exp(e-m) computed inline,
// denominator accumulated alongside; normalize at the end.
// ---------------------------------------------------------------------------
__global__ __launch_bounds__(512)
void gat_aggregate4(const unsigned short* __restrict__ hb,
                    const float* __restrict__ si, const float* __restrict__ sj,
                    const int* __restrict__ off, const int* __restrict__ ssrc,
                    float* __restrict__ aggbuf, int N) {
  int head = blockIdx.x & 7;
  int n = (blockIdx.x >> 3) * 8 + (threadIdx.x >> 6);
  if (n >= N) return;
  int lane = threadIdx.x & 63;
  int grp = lane >> 4;
  int l = lane & 15;
  const unsigned short* hbase = hb + (size_t)head * N * HID;
  int begin = off[n], end = off[n + 1];
  float s_i = si[n * HEADS + head];

  // pass 1: max over this (n, head)'s edges
  float m = -INFINITY;
  for (int k0 = begin; k0 < end; k0 += 64) {
    int k = k0 + lane;
    if (k < end) {
      float e = s_i + sj[ssrc[k] * HEADS + head];
      e = e > 0.f ? e : 0.01f * e;
      m = fmaxf(m, e);
    }
  }
  #pragma unroll
  for (int o = 1; o <= 32; o <<= 1) m = fmaxf(m, __shfl_xor(m, o));

  // pass 2: gather + inline softmax weights
  float a0 = 0.f, a1 = 0.f, a2 = 0.f, a3 = 0.f;
  float a4 = 0.f, a5 = 0.f, a6 = 0.f, a7 = 0.f;
  float denom = 0.f;

  for (int k0 = begin; k0 < end; k0 += 8) {
    int ka = k0 + grp;
    int kb = k0 + 4 + grp;
    int kka = ka < end ? ka : begin;
    int kkb = kb < end ? kb : begin;
    int sa = ssrc[kka];
    int sb = ssrc[kkb];
    float ea = s_i + sj[sa * HEADS + head];
    ea = ea > 0.f ? ea : 0.01f * ea;
    float eb = s_i + sj[sb * HEADS + head];
    eb = eb > 0.f ? eb : 0.01f * eb;
    float wa = expf(ea - m);
    float wb = expf(eb - m);
    if (ka >= end) wa = 0.f;
    if (kb >= end) wb = 0.f;
    denom += wa + wb;
    int4 pa = *(const int4*)&hbase[(size_t)sa * HID + l * 8];
    int4 pb = *(const int4*)&hbase[(size_t)sb * HID + l * 8];
    a0 = fmaf(wa, bf2f((unsigned)pa.x & 0xffffu), a0);
    a1 = fmaf(wa, __uint_as_float((unsigned)pa.x & 0xffff0000u), a1);
    a2 = fmaf(wa, bf2f((unsigned)pa.y & 0xffffu), a2);
    a3 = fmaf(wa, __uint_as_float((unsigned)pa.y & 0xffff0000u), a3);
    a4 = fmaf(wa, bf2f((unsigned)pa.z & 0xffffu), a4);
    a5 = fmaf(wa, __uint_as_float((unsigned)pa.z & 0xffff0000u), a5);
    a6 = fmaf(wa, bf2f((unsigned)pa.w & 0xffffu), a6);
    a7 = fmaf(wa, __uint_as_float((unsigned)pa.w & 0xffff0000u), a7);
    a0 = fmaf(wb, bf2f((unsigned)pb.x & 0xffffu), a0);
    a1 = fmaf(wb, __uint_as_float((unsigned)pb.x & 0xffff0000u), a1);
    a2 = fmaf(wb, bf2f((unsigned)pb.y & 0xffffu), a2);
    a3 = fmaf(wb, __uint_as_float((unsigned)pb.y & 0xffff0000u), a3);
    a4 = fmaf(wb, bf2f((unsigned)pb.z & 0xffffu), a4);
    a5 = fmaf(wb, __uint_as_float((unsigned)pb.z & 0xffff0000u), a5);
    a6 = fmaf(wb, bf2f((unsigned)pb.w & 0xffffu), a6);
    a7 = fmaf(wb, __uint_as_float((unsigned)pb.w & 0xffff0000u), a7);
  }
  // reduce across the 4 edge groups (and the denominator)
  a0 += __shfl_xor(a0, 16); a1 += __shfl_xor(a1, 16);
  a2 += __shfl_xor(a2, 16); a3 += __shfl_xor(a3, 16);
  a4 += __shfl_xor(a4, 16); a5 += __shfl_xor(a5, 16);
  a6 += __shfl_xor(a6, 16); a7 += __shfl_xor(a7, 16);
  denom += __shfl_xor(denom, 16);
  a0 += __shfl_xor(a0, 32); a1 += __shfl_xor(a1, 32);
  a2 += __shfl_xor(a2, 32); a3 += __shfl_xor(a3, 32);
  a4 += __shfl_xor(a4, 32); a5 += __shfl_xor(a5, 32);
  a6 += __shfl_xor(a6, 32); a7 += __shfl_xor(a7, 32);
  denom += __shfl_xor(denom, 32);

  if (grp == 0) {
    float inv = denom > 0.f ? 1.0f / denom : 0.f;
    float* dst = aggbuf + ((size_t)head * N + n) * HID + l * 8;
    *(float4*)dst = make_float4(a0 * inv, a1 * inv, a2 * inv, a3 * inv);
    *(float4*)(dst + 4) = make_float4(a4 * inv, a5 * inv, a6 * inv, a7 * inv);
  }
}

// ---------------------------------------------------------------------------
// Head mean + ELU, writing layer-2 A directly in frag-major split form
// ---------------------------------------------------------------------------
__global__ __launch_bounds__(256)
void headmean_frag(const float* __restrict__ aggbuf, unsigned short* __restrict__ hi,
                   unsigned short* __restrict__ lo, int N) {
  int idx = blockIdx.x * 256 + threadIdx.x;   // (rb,kq,r), K8=16
  int total = ((N + 15) / 16) * 256;
  if (idx >= total) return;
  int r = idx & 15;
  int kq = (idx >> 4) & 15;
  int rb = idx >> 8;
  int n = rb * 16 + r;
  float s[8] = {0.f, 0.f, 0.f, 0.f, 0.f, 0.f, 0.f, 0.f};
  if (n < N) {
    #pragma unroll
    for (int hh = 0; hh < HEADS; ++hh) {
      const float* p = aggbuf + ((size_t)hh * N + n) * HID + kq * 8;
      float4 p0 = *(const float4*)p;
      float4 p1 = *(const float4*)(p + 4);
      s[0] += p0.x; s[1] += p0.y; s[2] += p0.z; s[3] += p0.w;
      s[4] += p1.x; s[5] += p1.y; s[6] += p1.z; s[7] += p1.w;
    }
  }
  union { unsigned short u[8]; int4 v4; } H, L;
  #pragma unroll
  for (int e = 0; e < 8; ++e) {
    float v = s[e] * (1.0f / HEADS);
    v = v > 0.f ? v : (expf(v) - 1.0f);   // ELU
    unsigned short hb_ = f2bf_rne(v);
    H.u[e] = hb_;
    L.u[e] = f2bf_rne(v - bf2f(hb_));
  }
  *(int4*)&hi[(size_t)idx * 8] = H.v4;
  *(int4*)&lo[(size_t)idx * 8] = L.v4;
}

// ---------------------------------------------------------------------------
// Head mean + ELU -> fp32 emb (layer 2 output, feeds pooling)
// ---------------------------------------------------------------------------
__global__ __launch_bounds__(256)
void headmean_emb(const float* __restrict__ aggbuf, float* __restrict__ emb, int N) {
  int i = blockIdx.x * blockDim.x + threadIdx.x;
  if (i >= N * 64) return;
  float sx = 0.f, sy = 0.f;
  #pragma unroll
  for (int hh = 0; hh < HEADS; ++hh) {
    float2 v = ((const float2*)aggbuf)[(size_t)hh * N * 64 + i];
    sx += v.x; sy += v.y;
  }
  sx *= (1.0f / HEADS); sy *= (1.0f / HEADS);
  float ox = sx > 0.f ? sx : (expf(sx) - 1.0f);
  float oy = sy > 0.f ? sy : (expf(sy) - 1.0f);
  ((float2*)emb)[i] = make_float2(ox, oy);
}

// ---------------------------------------------------------------------------
// Graph pooling
// ---------------------------------------------------------------------------
__global__ __launch_bounds__(256)
void pool_kernel(const float* __restrict__ emb, float* __restrict__ g, int N) {
  __shared__ float part[256];
  int d = threadIdx.x & 127;
  int half = threadIdx.x >> 7;
  int n0 = blockIdx.x * 100;
  float s = 0.f;
  for (int i = half; i < 100; i += 2) {
    int n = n0 + i;
    if (n < N) s += emb[(size_t)n * HID + d];
  }
  part[threadIdx.x] = s;
  __syncthreads();
  if (threadIdx.x < HID) atomicAdd(&g[d], part[threadIdx.x] + part[128 + threadIdx.x]);
}

// ---------------------------------------------------------------------------
// LayerNorm + MLP head
// ---------------------------------------------------------------------------
__global__ __launch_bounds__(128)
void mlp_kernel(const float* __restrict__ g, const float* __restrict__ ln_g,
                const float* __restrict__ ln_b, const float* __restrict__ Wl1,
                const float* __restrict__ bl1, const float* __restrict__ Wl2,
                const float* __restrict__ bl2, const float* __restrict__ Wl3,
                const float* __restrict__ bl3, float* __restrict__ out, float invN) {
  __shared__ float red[128];
  __shared__ float gn[128];
  __shared__ float x1[64];
  __shared__ float x2[16];
  int t = threadIdx.x;
  float gg = g[t] * invN;
  red[t] = gg;
  __syncthreads();
  for (int o = 64; o > 0; o >>= 1) {
    if (t < o) red[t] += red[t + o];
    __syncthreads();
  }
  float mu = red[0] * (1.0f / HID);
  __syncthreads();
  float dv = gg - mu;
  red[t] = dv * dv;
  __syncthreads();
  for (int o = 64; o > 0; o >>= 1) {
    if (t < o) red[t] += red[t + o];
    __syncthreads();
  }
  float var = red[0] * (1.0f / HID);
  gn[t] = dv / sqrtf(var + 1e-5f) * ln_g[t] + ln_b[t];
  __syncthreads();
  if (t < 64) {
    float s = bl1[t];
    for (int k = 0; k < 128; ++k) s += Wl1[t * 128 + k] * gn[k];
    x1[t] = s > 0.f ? s : 0.01f * s;
  }
  __syncthreads();
  if (t < 16) {
    float s = bl2[t];
    for (int k = 0; k < 64; ++k) s += Wl2[t * 64 + k] * x1[k];
    x2[t] = s > 0.f ? s : 0.01f * s;
  }
  __syncthreads();
  if (t < 16) {
    float s = bl3[t];
    for (int k = 0; k < 16; ++k) s += Wl3[t * 16 + k] * x2[k];
    out[t] = s > 0.f ? s : 0.f;
  }
}

// ---------------------------------------------------------------------------
extern "C" void kernel_launch(void* const* d_in, const int* in_sizes, int n_in,
                              void* d_out, int out_size, void* d_ws, size_t ws_size,
                              hipStream_t stream) {
  const float* x    = (const float*)d_in[0];
  const int*   esrc = (const int*)d_in[1];
  const int*   edst = (const int*)d_in[2];
  const float* W1   = (const float*)d_in[3];
  const float* a1   = (const float*)d_in[4];
  const float* W2   = (const float*)d_in[5];
  const float* a2   = (const float*)d_in[6];
  const float* ln_g = (const float*)d_in[7];
  const float* ln_b = (const float*)d_in[8];
  const float* Wl1  = (const float*)d_in[9];
  const float* bl1  = (const float*)d_in[10];
  const float* Wl2  = (const float*)d_in[11];
  const float* bl2  = (const float*)d_in[12];
  const float* Wl3  = (const float*)d_in[13];
  const float* bl3  = (const float*)d_in[14];
  float* out = (float*)d_out;

  const int RBPAD = 640;  // row-blocks padded (10240 rows) for in-bounds frags

  float* ws   = (float*)d_ws;
  float* aggbuf = ws;                                   // 10,240,000 f (41 MB)
  float* si   = aggbuf + (size_t)N_NODES * HEADS * HID; // 80,000
  float* sj   = si + N_NODES * HEADS;                   // 80,000
  float* emb2 = sj + N_NODES * HEADS;                   // 1,280,000
  float* g    = emb2 + (size_t)N_NODES * HID;           // 128
  int*   deg  = (int*)(g + 128);                        // 10,000
  int*   off  = deg + N_NODES;                          // 10,001
  int*   ssrc = off + (N_NODES + 1);                    // 160,000
  unsigned short* Afh = (unsigned short*)(ssrc + N_EDGES + 3);  // 640*64*128 us
  unsigned short* Afl = Afh + (size_t)RBPAD * 64 * 128;
  unsigned short* Bfh = Afl + (size_t)RBPAD * 64 * 128;
  unsigned short* Bfl = Bfh + (size_t)64 * 64 * 128;
  unsigned short* hb  = Bfl + (size_t)64 * 64 * 128;            // 20.5 MB

  // CSR by dst
  hipMemsetAsync(deg, 0, N_NODES * sizeof(int), stream);
  count_kernel<<<(N_EDGES + 255) / 256, 256, 0, stream>>>(edst, deg, N_EDGES);
  scan_kernel<<<1, 1024, 0, stream>>>(deg, off, N_NODES);
  hipMemsetAsync(deg, 0, N_NODES * sizeof(int), stream);
  fill_kernel<<<(N_EDGES + 255) / 256, 256, 0, stream>>>(esrc, edst, off, deg, ssrc, N_EDGES);

  int gemmGrid = 160 * HEADS;                 // 1280 blocks of 128 threads
  int aggGrid = (N_NODES / 8) * 8;
  int hmGrid = (N_NODES * 64 + 255) / 256;

  // ---- Layer 1 ----
  {
    int totalA = RBPAD * 64 * 16;             // 16B units, K8=64
    split_frag<<<(totalA + 255) / 256, 256, 0, stream>>>(x, Afh, Afl, N_NODES, 64, totalA);
    int totalB = 64 * 64 * 16;                // 1024 rows, K8=64
    split_frag<<<(totalB + 255) / 256, 256, 0, stream>>>(W1, Bfh, Bfl, HEADS * HID, 64, totalB);
    gemm_frag<<<gemmGrid, 128, 0, stream>>>(Afh, Afl, Bfh, Bfl, a1, hb,
                                            si, sj, N_NODES, N_FEAT);
  }
  gat_aggregate4<<<aggGrid, 512, 0, stream>>>(hb, si, sj, off, ssrc, aggbuf, N_NODES);
  {
    int totalHM = ((N_NODES + 15) / 16) * 256;
    headmean_frag<<<(totalHM + 255) / 256, 256, 0, stream>>>(aggbuf, Afh, Afl, N_NODES);
  }

  // ---- Layer 2 ----
  {
    int totalB = 64 * 16 * 16;                // 1024 rows, K8=16
    split_frag<<<(totalB + 255) / 256, 256, 0, stream>>>(W2, Bfh, Bfl, HEADS * HID, 16, totalB);
    gemm_frag<<<gemmGrid, 128, 0, stream>>>(Afh, Afl, Bfh, Bfl, a2, hb,
                                            si, sj, N_NODES, HID);
  }
  gat_aggregate4<<<aggGrid, 512, 0, stream>>>(hb, si, sj, off, ssrc, aggbuf, N_NODES);
  headmean_emb<<<hmGrid, 256, 0, stream>>>(aggbuf, emb2, N_NODES);

  // ---- Pool + MLP head ----
  hipMemsetAsync(g, 0, HID * sizeof(float), stream);
  pool_kernel<<<100, 256, 0, stream>>>(emb2, g, N_NODES);
  mlp_kernel<<<1, 128, 0, stream>>>(g, ln_g, ln_b, Wl1, bl1, Wl2, bl2, Wl3, bl3,
                                    out, 1.0f / N_NODES);
}

// Round 10
// 336.967 us; speedup vs baseline: 1.0230x; 1.0230x over previous
//
#include <hip/hip_runtime.h>
#include <math.h>

#define N_NODES 10000
#define N_EDGES 160000
#define N_FEAT  512
#define HEADS   8
#define HID     128

typedef __attribute__((ext_vector_type(8))) short bf16x8;
typedef __attribute__((ext_vector_type(4))) float f32x4;

// ---------------------------------------------------------------------------
// fp32 <-> bf16 helpers
// ---------------------------------------------------------------------------
__device__ inline unsigned short f2bf_rne(float f) {
  unsigned int u = __float_as_uint(f);
  unsigned int r = u + 0x7fffu + ((u >> 16) & 1u);
  return (unsigned short)(r >> 16);
}
__device__ inline float bf2f(unsigned int b) {
  return __uint_as_float(b << 16);
}

// ---------------------------------------------------------------------------
// Split fp32 [R][K] into hi/lo bf16 in MFMA-fragment-major layout:
// unit (rb,kq,r) at index (rb*K8+kq)*16+r holds 8 bf16 = A[rb*16+r][kq*8..+8].
// ---------------------------------------------------------------------------
__global__ __launch_bounds__(256)
void split_frag(const float* __restrict__ in, unsigned short* __restrict__ hi,
                unsigned short* __restrict__ lo, int R, int K8, int total) {
  int idx = blockIdx.x * 256 + threadIdx.x;
  if (idx >= total) return;
  int r = idx & 15;
  int t = idx >> 4;
  int kq = t % K8;
  int rb = t / K8;
  int row = rb * 16 + r;
  float v[8] = {0.f, 0.f, 0.f, 0.f, 0.f, 0.f, 0.f, 0.f};
  if (row < R) {
    const float* p = in + (size_t)row * (K8 * 8) + kq * 8;
    float4 a = *(const float4*)p;
    float4 b = *(const float4*)(p + 4);
    v[0] = a.x; v[1] = a.y; v[2] = a.z; v[3] = a.w;
    v[4] = b.x; v[5] = b.y; v[6] = b.z; v[7] = b.w;
  }
  union { unsigned short u[8]; int4 v4; } H, L;
  #pragma unroll
  for (int e = 0; e < 8; ++e) {
    unsigned short hb_ = f2bf_rne(v[e]);
    H.u[e] = hb_;
    L.u[e] = f2bf_rne(v[e] - bf2f(hb_));
  }
  *(int4*)&hi[(size_t)idx * 8] = H.v4;
  *(int4*)&lo[(size_t)idx * 8] = L.v4;
}

// ---------------------------------------------------------------------------
// LDS-free split-bf16 MFMA GEMM with register double-buffered K-loop
// (R9 version — kept: loads stay in flight across the MFMA block).
// ---------------------------------------------------------------------------
#define LOAD_SET(AH, AL, BH, BL, AI, BI)                                      \
  _Pragma("unroll")                                                           \
  for (int i = 0; i < 4; ++i) {                                               \
    AH[i] = pAh[(AI) + i * rstep]; AL[i] = pAl[(AI) + i * rstep];             \
    BH[i] = pBh[(BI) + i * rstep]; BL[i] = pBl[(BI) + i * rstep];             \
  }

#define MFMA_TRIPLE(AH, AL, BH, BL)                                           \
  _Pragma("unroll")                                                           \
  for (int i = 0; i < 4; ++i) {                                               \
    _Pragma("unroll")                                                         \
    for (int j = 0; j < 4; ++j) {                                             \
      acc[i][j] = __builtin_amdgcn_mfma_f32_16x16x32_bf16(AH[i], BH[j], acc[i][j], 0, 0, 0); \
      acc[i][j] = __builtin_amdgcn_mfma_f32_16x16x32_bf16(AH[i], BL[j], acc[i][j], 0, 0, 0); \
      acc[i][j] = __builtin_amdgcn_mfma_f32_16x16x32_bf16(AL[i], BH[j], acc[i][j], 0, 0, 0); \
    }                                                                         \
  }

__global__ __launch_bounds__(128, 2)
void gemm_frag(const unsigned short* __restrict__ Afh,
               const unsigned short* __restrict__ Afl,
               const unsigned short* __restrict__ Bfh,
               const unsigned short* __restrict__ Bfl,
               const float* __restrict__ avec,
               unsigned short* __restrict__ hb,
               float* __restrict__ si, float* __restrict__ sj,
               int M, int K) {
  __shared__ float rsi[64][2];
  __shared__ float rsj[64][2];
  int tid = threadIdx.x;
  int wave = tid >> 6, lane = tid & 63;
  int r = lane & 15, q = lane >> 4;

  int blk = blockIdx.x;
  int rr = blk & 7, gg = blk >> 3;
  int head = gg & 7;
  int mtile = (gg >> 3) * 8 + rr;     // blk%8 == mtile%8 -> XCD affinity
  int m0 = mtile * 64;
  int wn = wave * 64;
  int K8 = K >> 3;

  const bf16x8* pAh = (const bf16x8*)Afh;
  const bf16x8* pAl = (const bf16x8*)Afl;
  const bf16x8* pBh = (const bf16x8*)Bfh;
  const bf16x8* pBl = (const bf16x8*)Bfl;
  size_t rstep = (size_t)K8 * 16;
  size_t aidx = (size_t)(m0 >> 4) * rstep + (size_t)q * 16 + r;
  size_t bidx = (size_t)(head * 8 + (wn >> 4)) * rstep + (size_t)q * 16 + r;

  f32x4 acc[4][4] = {};
  bf16x8 ah0[4], al0[4], bh0[4], bl0[4];
  bf16x8 ah1[4], al1[4], bh1[4], bl1[4];

  LOAD_SET(ah0, al0, bh0, bl0, aidx, bidx);
  for (int k0 = 0; k0 < K; k0 += 64) {
    LOAD_SET(ah1, al1, bh1, bl1, aidx + 64, bidx + 64);
    MFMA_TRIPLE(ah0, al0, bh0, bl0);
    aidx += 128; bidx += 128;
    if (k0 + 64 < K) {
      LOAD_SET(ah0, al0, bh0, bl0, aidx, bidx);
    }
    MFMA_TRIPLE(ah1, al1, bh1, bl1);
  }

  // --- epilogue: C/D layout col = r, row = q*4 + reg (per 16x16 frag) ---
  const float* av = avec + (size_t)head * (2 * HID);
  float aiv[4], ajv[4];
  #pragma unroll
  for (int j = 0; j < 4; ++j) {
    int c = wn + j * 16 + r;
    aiv[j] = av[c];
    ajv[j] = av[HID + c];
  }
  #pragma unroll
  for (int i = 0; i < 4; ++i) {
    #pragma unroll
    for (int reg = 0; reg < 4; ++reg) {
      int lrow = i * 16 + q * 4 + reg;
      int row = m0 + lrow;
      float vsi = 0.f, vsj = 0.f;
      #pragma unroll
      for (int j = 0; j < 4; ++j) {
        float v = acc[i][j][reg];
        vsi = fmaf(v, aiv[j], vsi);
        vsj = fmaf(v, ajv[j], vsj);
        if (row < M)
          hb[((size_t)head * M + row) * HID + wn + j * 16 + r] = f2bf_rne(v);
      }
      #pragma unroll
      for (int o = 8; o >= 1; o >>= 1) {
        vsi += __shfl_xor(vsi, o);
        vsj += __shfl_xor(vsj, o);
      }
      if (r == 0) {
        rsi[lrow][wave] = vsi;
        rsj[lrow][wave] = vsj;
      }
    }
  }
  __syncthreads();
  if (tid < 64) {
    int row = m0 + tid;
    if (row < M) {
      si[(size_t)row * HEADS + head] = rsi[tid][0] + rsi[tid][1];
      sj[(size_t)row * HEADS + head] = rsj[tid][0] + rsj[tid][1];
    }
  }
}

// ---------------------------------------------------------------------------
// CSR build
// ---------------------------------------------------------------------------
__global__ void count_kernel(const int* __restrict__ dst, int* __restrict__ deg, int E) {
  int e = blockIdx.x * blockDim.x + threadIdx.x;
  if (e < E) atomicAdd(&deg[dst[e]], 1);
}

__global__ __launch_bounds__(1024)
void scan_kernel(const int* __restrict__ deg, int* __restrict__ off, int N) {
  __shared__ int sums[1024];
  const int PER = 10;
  int tid = threadIdx.x;
  int base = tid * PER;
  int loc[PER];
  int run = 0;
  #pragma unroll
  for (int j = 0; j < PER; ++j) {
    int v = (base + j < N) ? deg[base + j] : 0;
    run += v;
    loc[j] = run;
  }
  sums[tid] = run;
  __syncthreads();
  for (int o = 1; o < 1024; o <<= 1) {
    int v = (tid >= o) ? sums[tid - o] : 0;
    __syncthreads();
    sums[tid] += v;
    __syncthreads();
  }
  int ex = sums[tid] - run;
  if (tid == 0) off[0] = 0;
  #pragma unroll
  for (int j = 0; j < PER; ++j)
    if (base + j < N) off[base + j + 1] = ex + loc[j];
}

__global__ void fill_kernel(const int* __restrict__ src, const int* __restrict__ dst,
                            const int* __restrict__ off, int* __restrict__ cursor,
                            int* __restrict__ ssrc, int E) {
  int e = blockIdx.x * blockDim.x + threadIdx.x;
  if (e < E) {
    int d = dst[e];
    int p = atomicAdd(&cursor[d], 1);
    ssrc[off[d] + p] = src[e];
  }
}

// ---------------------------------------------------------------------------
// Edge softmax weights (R8 design — one exp per (edge,head), fully parallel):
// one wave per dst node, lane = eidx*8 + head.
// ---------------------------------------------------------------------------
__global__ __launch_bounds__(256)
void alpha_kernel(const float* __restrict__ si, const float* __restrict__ sj,
                  const int* __restrict__ off, const int* __restrict__ ssrc,
                  float* __restrict__ w, float* __restrict__ invden, int N) {
  int wv = (blockIdx.x * blockDim.x + threadIdx.x) >> 6;
  if (wv >= N) return;
  int lane = threadIdx.x & 63;
  int eidx = lane >> 3, head = lane & 7;
  int begin = off[wv], end = off[wv + 1];
  float s_i = si[wv * HEADS + head];

  float m = -INFINITY;
  for (int k0 = begin; k0 < end; k0 += 8) {
    int k = k0 + eidx;
    if (k < end) {
      float e = s_i + sj[ssrc[k] * HEADS + head];
      e = e > 0.f ? e : 0.01f * e;
      m = fmaxf(m, e);
    }
  }
  m = fmaxf(m, __shfl_xor(m, 8));
  m = fmaxf(m, __shfl_xor(m, 16));
  m = fmaxf(m, __shfl_xor(m, 32));

  float sum = 0.f;
  for (int k0 = begin; k0 < end; k0 += 8) {
    int k = k0 + eidx;
    if (k < end) {
      float e = s_i + sj[ssrc[k] * HEADS + head];
      e = e > 0.f ? e : 0.01f * e;
      float wt = expf(e - m);
      w[(size_t)k * HEADS + head] = wt;
      sum += wt;
    }
  }
  sum += __shfl_xor(sum, 8);
  sum += __shfl_xor(sum, 16);
  sum += __shfl_xor(sum, 32);
  if (eidx == 0)
    invden[wv * HEADS + head] = sum > 0.f ? 1.0f / sum : 0.f;
}

// ---------------------------------------------------------------------------
// Aggregation (R8 design, deepened): one wave per (dst, head);
// head = blockIdx.x & 7 (XCD/L2 affinity on head-major hb).
// Wave = 4 groups x 16 lanes; each group handles one edge, each lane 16B.
// 4x unrolled -> 16 edge-vectors in flight per wave.
// ---------------------------------------------------------------------------
__global__ __launch_bounds__(512)
void gat_aggregate3(const unsigned short* __restrict__ hb,
                    const float* __restrict__ w, const float* __restrict__ invden,
                    const int* __restrict__ off, const int* __restrict__ ssrc,
                    float* __restrict__ aggbuf, int N) {
  int head = blockIdx.x & 7;
  int n = (blockIdx.x >> 3) * 8 + (threadIdx.x >> 6);
  if (n >= N) return;
  int lane = threadIdx.x & 63;
  int grp = lane >> 4;
  int l = lane & 15;
  const unsigned short* hbase = hb + (size_t)head * N * HID;
  int begin = off[n], end = off[n + 1];

  float a0 = 0.f, a1 = 0.f, a2 = 0.f, a3 = 0.f;
  float a4 = 0.f, a5 = 0.f, a6 = 0.f, a7 = 0.f;

  for (int k0 = begin; k0 < end; k0 += 16) {
    int kk[4];
    float wv[4];
    int sv[4];
    #pragma unroll
    for (int u = 0; u < 4; ++u) {
      int k = k0 + u * 4 + grp;
      kk[u] = k < end ? k : begin;
      sv[u] = ssrc[kk[u]];
      wv[u] = w[(size_t)kk[u] * HEADS + head];
      if (k >= end) wv[u] = 0.f;
    }
    int4 pv[4];
    #pragma unroll
    for (int u = 0; u < 4; ++u)
      pv[u] = *(const int4*)&hbase[(size_t)sv[u] * HID + l * 8];
    #pragma unroll
    for (int u = 0; u < 4; ++u) {
      float wu = wv[u];
      int4 p = pv[u];
      a0 = fmaf(wu, bf2f((unsigned)p.x & 0xffffu), a0);
      a1 = fmaf(wu, __uint_as_float((unsigned)p.x & 0xffff0000u), a1);
      a2 = fmaf(wu, bf2f((unsigned)p.y & 0xffffu), a2);
      a3 = fmaf(wu, __uint_as_float((unsigned)p.y & 0xffff0000u), a3);
      a4 = fmaf(wu, bf2f((unsigned)p.z & 0xffffu), a4);
      a5 = fmaf(wu, __uint_as_float((unsigned)p.z & 0xffff0000u), a5);
      a6 = fmaf(wu, bf2f((unsigned)p.w & 0xffffu), a6);
      a7 = fmaf(wu, __uint_as_float((unsigned)p.w & 0xffff0000u), a7);
    }
  }
  a0 += __shfl_xor(a0, 16); a1 += __shfl_xor(a1, 16);
  a2 += __shfl_xor(a2, 16); a3 += __shfl_xor(a3, 16);
  a4 += __shfl_xor(a4, 16); a5 += __shfl_xor(a5, 16);
  a6 += __shfl_xor(a6, 16); a7 += __shfl_xor(a7, 16);
  a0 += __shfl_xor(a0, 32); a1 += __shfl_xor(a1, 32);
  a2 += __shfl_xor(a2, 32); a3 += __shfl_xor(a3, 32);
  a4 += __shfl_xor(a4, 32); a5 += __shfl_xor(a5, 32);
  a6 += __shfl_xor(a6, 32); a7 += __shfl_xor(a7, 32);

  if (grp == 0) {
    float inv = invden[n * HEADS + head];
    float* dst = aggbuf + ((size_t)head * N + n) * HID + l * 8;
    *(float4*)dst = make_float4(a0 * inv, a1 * inv, a2 * inv, a3 * inv);
    *(float4*)(dst + 4) = make_float4(a4 * inv, a5 * inv, a6 * inv, a7 * inv);
  }
}

// ---------------------------------------------------------------------------
// Head mean + ELU, writing layer-2 A directly in frag-major split form
// ---------------------------------------------------------------------------
__global__ __launch_bounds__(256)
void headmean_frag(const float* __restrict__ aggbuf, unsigned short* __restrict__ hi,
                   unsigned short* __restrict__ lo, int N) {
  int idx = blockIdx.x * 256 + threadIdx.x;   // (rb,kq,r), K8=16
  int total = ((N + 15) / 16) * 256;
  if (idx >= total) return;
  int r = idx & 15;
  int kq = (idx >> 4) & 15;
  int rb = idx >> 8;
  int n = rb * 16 + r;
  float s[8] = {0.f, 0.f, 0.f, 0.f, 0.f, 0.f, 0.f, 0.f};
  if (n < N) {
    #pragma unroll
    for (int hh = 0; hh < HEADS; ++hh) {
      const float* p = aggbuf + ((size_t)hh * N + n) * HID + kq * 8;
      float4 p0 = *(const float4*)p;
      float4 p1 = *(const float4*)(p + 4);
      s[0] += p0.x; s[1] += p0.y; s[2] += p0.z; s[3] += p0.w;
      s[4] += p1.x; s[5] += p1.y; s[6] += p1.z; s[7] += p1.w;
    }
  }
  union { unsigned short u[8]; int4 v4; } H, L;
  #pragma unroll
  for (int e = 0; e < 8; ++e) {
    float v = s[e] * (1.0f / HEADS);
    v = v > 0.f ? v : (expf(v) - 1.0f);   // ELU
    unsigned short hb_ = f2bf_rne(v);
    H.u[e] = hb_;
    L.u[e] = f2bf_rne(v - bf2f(hb_));
  }
  *(int4*)&hi[(size_t)idx * 8] = H.v4;
  *(int4*)&lo[(size_t)idx * 8] = L.v4;
}

// ---------------------------------------------------------------------------
// Head mean + ELU -> fp32 emb (layer 2 output, feeds pooling)
// ---------------------------------------------------------------------------
__global__ __launch_bounds__(256)
void headmean_emb(const float* __restrict__ aggbuf, float* __restrict__ emb, int N) {
  int i = blockIdx.x * blockDim.x + threadIdx.x;
  if (i >= N * 64) return;
  float sx = 0.f, sy = 0.f;
  #pragma unroll
  for (int hh = 0; hh < HEADS; ++hh) {
    float2 v = ((const float2*)aggbuf)[(size_t)hh * N * 64 + i];
    sx += v.x; sy += v.y;
  }
  sx *= (1.0f / HEADS); sy *= (1.0f / HEADS);
  float ox = sx > 0.f ? sx : (expf(sx) - 1.0f);
  float oy = sy > 0.f ? sy : (expf(sy) - 1.0f);
  ((float2*)emb)[i] = make_float2(ox, oy);
}

// ---------------------------------------------------------------------------
// Graph pooling
// ---------------------------------------------------------------------------
__global__ __launch_bounds__(256)
void pool_kernel(const float* __restrict__ emb, float* __restrict__ g, int N) {
  __shared__ float part[256];
  int d = threadIdx.x & 127;
  int half = threadIdx.x >> 7;
  int n0 = blockIdx.x * 100;
  float s = 0.f;
  for (int i = half; i < 100; i += 2) {
    int n = n0 + i;
    if (n < N) s += emb[(size_t)n * HID + d];
  }
  part[threadIdx.x] = s;
  __syncthreads();
  if (threadIdx.x < HID) atomicAdd(&g[d], part[threadIdx.x] + part[128 + threadIdx.x]);
}

// ---------------------------------------------------------------------------
// LayerNorm + MLP head
// ---------------------------------------------------------------------------
__global__ __launch_bounds__(128)
void mlp_kernel(const float* __restrict__ g, const float* __restrict__ ln_g,
                const float* __restrict__ ln_b, const float* __restrict__ Wl1,
                const float* __restrict__ bl1, const float* __restrict__ Wl2,
                const float* __restrict__ bl2, const float* __restrict__ Wl3,
                const float* __restrict__ bl3, float* __restrict__ out, float invN) {
  __shared__ float red[128];
  __shared__ float gn[128];
  __shared__ float x1[64];
  __shared__ float x2[16];
  int t = threadIdx.x;
  float gg = g[t] * invN;
  red[t] = gg;
  __syncthreads();
  for (int o = 64; o > 0; o >>= 1) {
    if (t < o) red[t] += red[t + o];
    __syncthreads();
  }
  float mu = red[0] * (1.0f / HID);
  __syncthreads();
  float dv = gg - mu;
  red[t] = dv * dv;
  __syncthreads();
  for (int o = 64; o > 0; o >>= 1) {
    if (t < o) red[t] += red[t + o];
    __syncthreads();
  }
  float var = red[0] * (1.0f / HID);
  gn[t] = dv / sqrtf(var + 1e-5f) * ln_g[t] + ln_b[t];
  __syncthreads();
  if (t < 64) {
    float s = bl1[t];
    for (int k = 0; k < 128; ++k) s += Wl1[t * 128 + k] * gn[k];
    x1[t] = s > 0.f ? s : 0.01f * s;
  }
  __syncthreads();
  if (t < 16) {
    float s = bl2[t];
    for (int k = 0; k < 64; ++k) s += Wl2[t * 64 + k] * x1[k];
    x2[t] = s > 0.f ? s : 0.01f * s;
  }
  __syncthreads();
  if (t < 16) {
    float s = bl3[t];
    for (int k = 0; k < 16; ++k) s += Wl3[t * 16 + k] * x2[k];
    out[t] = s > 0.f ? s : 0.f;
  }
}

// ---------------------------------------------------------------------------
extern "C" void kernel_launch(void* const* d_in, const int* in_sizes, int n_in,
                              void* d_out, int out_size, void* d_ws, size_t ws_size,
                              hipStream_t stream) {
  const float* x    = (const float*)d_in[0];
  const int*   esrc = (const int*)d_in[1];
  const int*   edst = (const int*)d_in[2];
  const float* W1   = (const float*)d_in[3];
  const float* a1   = (const float*)d_in[4];
  const float* W2   = (const float*)d_in[5];
  const float* a2   = (const float*)d_in[6];
  const float* ln_g = (const float*)d_in[7];
  const float* ln_b = (const float*)d_in[8];
  const float* Wl1  = (const float*)d_in[9];
  const float* bl1  = (const float*)d_in[10];
  const float* Wl2  = (const float*)d_in[11];
  const float* bl2  = (const float*)d_in[12];
  const float* Wl3  = (const float*)d_in[13];
  const float* bl3  = (const float*)d_in[14];
  float* out = (float*)d_out;

  const int RBPAD = 640;  // row-blocks padded (10240 rows) for in-bounds frags

  float* ws   = (float*)d_ws;
  float* aggbuf = ws;                                   // 10,240,000 f (41 MB)
  float* si   = aggbuf + (size_t)N_NODES * HEADS * HID; // 80,000
  float* sj   = si + N_NODES * HEADS;                   // 80,000
  float* emb2 = sj + N_NODES * HEADS;                   // 1,280,000
  float* g    = emb2 + (size_t)N_NODES * HID;           // 128
  float* wbuf = g + 128;                                // 1,280,000
  float* invd = wbuf + (size_t)N_EDGES * HEADS;         // 80,000
  int*   deg  = (int*)(invd + N_NODES * HEADS);         // 10,000
  int*   off  = deg + N_NODES;                          // 10,001
  int*   ssrc = off + (N_NODES + 1);                    // 160,000
  unsigned short* Afh = (unsigned short*)(ssrc + N_EDGES + 3);  // 640*64*128 us
  unsigned short* Afl = Afh + (size_t)RBPAD * 64 * 128;
  unsigned short* Bfh = Afl + (size_t)RBPAD * 64 * 128;
  unsigned short* Bfl = Bfh + (size_t)64 * 64 * 128;
  unsigned short* hb  = Bfl + (size_t)64 * 64 * 128;            // 20.5 MB

  // CSR by dst
  hipMemsetAsync(deg, 0, N_NODES * sizeof(int), stream);
  count_kernel<<<(N_EDGES + 255) / 256, 256, 0, stream>>>(edst, deg, N_EDGES);
  scan_kernel<<<1, 1024, 0, stream>>>(deg, off, N_NODES);
  hipMemsetAsync(deg, 0, N_NODES * sizeof(int), stream);
  fill_kernel<<<(N_EDGES + 255) / 256, 256, 0, stream>>>(esrc, edst, off, deg, ssrc, N_EDGES);

  int gemmGrid = 160 * HEADS;                 // 1280 blocks of 128 threads
  int aggGrid = (N_NODES / 8) * 8;
  int hmGrid = (N_NODES * 64 + 255) / 256;

  // ---- Layer 1 ----
  {
    int totalA = RBPAD * 64 * 16;             // 16B units, K8=64
    split_frag<<<(totalA + 255) / 256, 256, 0, stream>>>(x, Afh, Afl, N_NODES, 64, totalA);
    int totalB = 64 * 64 * 16;                // 1024 rows, K8=64
    split_frag<<<(totalB + 255) / 256, 256, 0, stream>>>(W1, Bfh, Bfl, HEADS * HID, 64, totalB);
    gemm_frag<<<gemmGrid, 128, 0, stream>>>(Afh, Afl, Bfh, Bfl, a1, hb,
                                            si, sj, N_NODES, N_FEAT);
  }
  alpha_kernel<<<(N_NODES + 3) / 4, 256, 0, stream>>>(si, sj, off, ssrc, wbuf, invd, N_NODES);
  gat_aggregate3<<<aggGrid, 512, 0, stream>>>(hb, wbuf, invd, off, ssrc, aggbuf, N_NODES);
  {
    int totalHM = ((N_NODES + 15) / 16) * 256;
    headmean_frag<<<(totalHM + 255) / 256, 256, 0, stream>>>(aggbuf, Afh, Afl, N_NODES);
  }

  // ---- Layer 2 ----
  {
    int totalB = 64 * 16 * 16;                // 1024 rows, K8=16
    split_frag<<<(totalB + 255) / 256, 256, 0, stream>>>(W2, Bfh, Bfl, HEADS * HID, 16, totalB);
    gemm_frag<<<gemmGrid, 128, 0, stream>>>(Afh, Afl, Bfh, Bfl, a2, hb,
                                            si, sj, N_NODES, HID);
  }
  alpha_kernel<<<(N_NODES + 3) / 4, 256, 0, stream>>>(si, sj, off, ssrc, wbuf, invd, N_NODES);
  gat_aggregate3<<<aggGrid, 512, 0, stream>>>(hb, wbuf, invd, off, ssrc, aggbuf, N_NODES);
  headmean_emb<<<hmGrid, 256, 0, stream>>>(aggbuf, emb2, N_NODES);

  // ---- Pool + MLP head ----
  hipMemsetAsync(g, 0, HID * sizeof(float), stream);
  pool_kernel<<<100, 256, 0, stream>>>(emb2, g, N_NODES);
  mlp_kernel<<<1, 128, 0, stream>>>(g, ln_g, ln_b, Wl1, bl1, Wl2, bl2, Wl3, bl3,
                                    out, 1.0f / N_NODES);
}